// Round 10
// baseline (53.625 us; speedup 1.0000x reference)
//
#include <hip/hip_runtime.h>
#include <hip/hip_bf16.h>
#include <hip/hip_fp16.h>

typedef unsigned int uint;
typedef unsigned short ushort;
typedef __attribute__((ext_vector_type(4))) float f32x4;
typedef __attribute__((ext_vector_type(8))) _Float16 f16x8;

// async global->LDS (used by tree_out staging only)
#define LDS16(gp, lp)                                                                    \
  __builtin_amdgcn_global_load_lds((const __attribute__((address_space(1))) uint*)(gp),  \
                                   (__attribute__((address_space(3))) uint*)(lp), 16, 0, 0)

// pack two f32 -> one u32 of two f16 (RTZ)
__device__ __forceinline__ uint pk_f16(float a, float b) {
  __fp16 __attribute__((ext_vector_type(2))) r = __builtin_amdgcn_cvt_pkrtz(a, b);
  union { decltype(r) v; uint u; } c;
  c.v = r;
  return c.u;
}

// ---------------------------------------------------------------------------
// Kernel 1: pack W (1024x511 f32, row-major) into MFMA-fragment-ordered f16
// via LDS transpose (both global sides coalesced):
// Bpk[((kt32*32 + ct16)*64 + lane)*8 + j] = W[kt32*32 + (lane>>4)*8 + j]
//                                            [ct16*16 + (lane&15)]  (0-pad c=511)
// ---------------------------------------------------------------------------
__global__ __launch_bounds__(256) void prep_b(const float* __restrict__ W,
                                              _Float16* __restrict__ Bpk) {
  __shared__ float t[64][65];
  const int tid = threadIdx.x;
  const int k0 = (blockIdx.x >> 3) * 64;  // 16 k-tiles
  const int c0 = (blockIdx.x & 7) * 64;   // 8 c-tiles
#pragma unroll
  for (int i = 0; i < 16; ++i) {
    int idx = i * 256 + tid;
    int kk = idx >> 6, cc = idx & 63;
    int c = c0 + cc;
    t[kk][cc] = (c < 511) ? W[(size_t)(k0 + kk) * 511 + c] : 0.f;
  }
  __syncthreads();
#pragma unroll
  for (int i = 0; i < 2; ++i) {
    int idx = i * 256 + tid;      // 0..511 = 8 frags x 64 lanes
    int fr = idx >> 6;            // local frag: kt(0..1) x ct(0..3)
    int lane = idx & 63;
    int kt = fr >> 2, ct = fr & 3;
    int kt32 = (k0 >> 5) + kt, ct16 = (c0 >> 4) + ct;
    f16x8 v;
#pragma unroll
    for (int j = 0; j < 8; ++j)
      v[j] = (_Float16)t[kt * 32 + (lane >> 4) * 8 + j][ct * 16 + (lane & 15)];
    *(f16x8*)&Bpk[(size_t)((kt32 * 32 + ct16) * 64 + lane) * 8] = v;
  }
}

// ---------------------------------------------------------------------------
// Kernel 2: P = sigmoid(X @ W + b), f16 [16384][512] (col 511 junk).
// BARRIER-FREE K-loop: full A-panel (64 rows x 1024 K, f16 = 128 KB) staged
// in LDS once (one __syncthreads), then 16 waves free-run independently.
// Wave tile 64x32 (1M x 16N). Per K-step: 2 packed-B loads (L2, 1KB/wave),
// 4 swizzled ds_read_b128, 8 MFMA. B double-buffered in regs (pure reg deps,
// no inline-asm waits). TLP (4 waves/SIMD, no fences) hides all latency.
// ---------------------------------------------------------------------------
__global__ __launch_bounds__(1024, 4) void gemm_sig(const float* __restrict__ X,
                                                    const _Float16* __restrict__ Bpk,
                                                    const float* __restrict__ bvec,
                                                    __half* __restrict__ P) {
  __shared__ _Float16 ldsA[64 * 1024];  // 128 KB: [row][k], 16B chunks XOR-swizzled

  const int tid = threadIdx.x;  // 0..1023
  const int lane = tid & 63;
  const int w = tid >> 6;       // wave 0..15 owns cols [w*32, w*32+32)
  const int l16 = lane & 15;
  const int g = lane >> 4;
  const int rbase = blockIdx.x * 64;

  // ---- prologue: stage full A panel, f32 -> f16, swizzled ----
  {
    const int sr = tid & 63;    // row
    const int skb = tid >> 6;   // k-block 0..15 (64 k-values = 8 chunks each)
    const float* sSrc = X + (size_t)(rbase + sr) * 1024 + skb * 64;
    f32x4 xr[16];
#pragma unroll
    for (int i = 0; i < 16; ++i) xr[i] = *(const f32x4*)(sSrc + i * 4);
#pragma unroll
    for (int j = 0; j < 8; ++j) {
      union { uint u[4]; f16x8 v; } cc;
      cc.u[0] = pk_f16(xr[2 * j][0], xr[2 * j][1]);
      cc.u[1] = pk_f16(xr[2 * j][2], xr[2 * j][3]);
      cc.u[2] = pk_f16(xr[2 * j + 1][0], xr[2 * j + 1][1]);
      cc.u[3] = pk_f16(xr[2 * j + 1][2], xr[2 * j + 1][3]);
      // global chunk c = skb*8 + j, swizzled slot within its 8-chunk window
      *(f16x8*)&ldsA[sr * 1024 + (skb * 8 + (j ^ (sr & 7))) * 8] = cc.v;
    }
  }
  __syncthreads();  // the ONLY barrier

  f32x4 acc[4][2];
#pragma unroll
  for (int i = 0; i < 4; ++i)
#pragma unroll
    for (int j = 0; j < 2; ++j) acc[i][j] = (f32x4)0.f;

  auto loadB = [&](f16x8* bR, int t) {  // 2 coalesced 1KB wave-loads from L2
#pragma unroll
    for (int ni = 0; ni < 2; ++ni)
      bR[ni] = *(const f16x8*)&Bpk[(size_t)((t * 32 + 2 * w + ni) * 64 + lane) * 8];
  };

  auto computeK = [&](int t, const f16x8* bR) {
    f16x8 a[4];
#pragma unroll
    for (int mi = 0; mi < 4; ++mi) {
      int r = mi * 16 + l16;
      int c = t * 4 + g;                             // global 16B chunk index
      int csw = (c & ~7) | ((c ^ (r & 7)) & 7);      // row-XOR swizzle
      a[mi] = *(const f16x8*)&ldsA[r * 1024 + csw * 8];
    }
#pragma unroll
    for (int mi = 0; mi < 4; ++mi)
#pragma unroll
      for (int ni = 0; ni < 2; ++ni)
        acc[mi][ni] = __builtin_amdgcn_mfma_f32_16x16x32_f16(a[mi], bR[ni], acc[mi][ni], 0, 0, 0);
  };

  f16x8 bA[2], bB[2];
  loadB(bA, 0);
#pragma unroll 1
  for (int t = 0; t < 32; t += 2) {
    loadB(bB, t + 1);            // prefetch next (reg dep, compiler-counted wait)
    computeK(t, bA);
    if (t + 2 < 32) loadB(bA, t + 2);
    computeK(t + 1, bB);
  }

  // epilogue: bias + sigmoid, store f16
#pragma unroll
  for (int ni = 0; ni < 2; ++ni) {
    int gc = (w << 5) + ni * 16 + l16;
    float bias = (gc < 511) ? bvec[gc] : 0.f;
#pragma unroll
    for (int mi = 0; mi < 4; ++mi) {
#pragma unroll
      for (int q = 0; q < 4; ++q) {
        int gr = rbase + mi * 16 + g * 4 + q;
        float z = acc[mi][ni][q] + bias;
        float pv = 1.f / (1.f + __expf(-z));
        P[(size_t)gr * 512 + gc] = __float2half(pv);
      }
    }
  }
}

// ---------------------------------------------------------------------------
// Kernel 3: tree propagation + leaf matmul (f16 MFMA).
// 1 block = 16 rows; 4 waves split the 16 t-chunks, partials reduced in LDS.
// ---------------------------------------------------------------------------
__global__ __launch_bounds__(256) void tree_out(const __half* __restrict__ P,
                                                const float* __restrict__ LL,
                                                float* __restrict__ out) {
  __shared__ __half plds[16 * 520];
  __shared__ f32x4 red[4][64];
  const int tid = threadIdx.x;
  const int lane = tid & 63;
  const int wid = tid >> 6;
  const int r = lane & 15;
  const int g = lane >> 4;
  const int rbase = blockIdx.x * 16;

#pragma unroll
  for (int i = 0; i < 4; ++i) {
    int row = wid * 4 + i;
    LDS16(P + (size_t)(rbase + row) * 512 + lane * 8, plds + row * 520 + lane * 8);
  }

  f16x8 bfr[4];
  const int col = r;
#pragma unroll
  for (int tt = 0; tt < 4; ++tt) {
    int t = wid * 4 + tt;
#pragma unroll
    for (int p = 0; p < 8; ++p) {
      int k0 = t * 32 + g * 8 + p;
      bfr[tt][p] = (col < 10) ? (_Float16)LL[k0 * 10 + col] : (_Float16)0.f;
    }
  }

  __syncthreads();

  const __half* prow = &plds[r * 520];
  f32x4 acc = (f32x4)0.f;
#pragma unroll
  for (int tt = 0; tt < 4; ++tt) {
    const int t = wid * 4 + tt;
    const int L0 = g * 8 + 32 * t;
    float pref = 1.f;
#pragma unroll
    for (int k = 0; k < 6; ++k) {
      int node = L0 >> (9 - k);
      int bit = (L0 >> (8 - k)) & 1;
      float pv = __half2float(prow[(1 << k) - 1 + node]);
      pref *= bit ? pv : (1.f - pv);
    }
    float p6 = __half2float(prow[63 + (L0 >> 3)]);
    float p7a = __half2float(prow[127 + (L0 >> 2)]);
    float p7b = __half2float(prow[128 + (L0 >> 2)]);
    float p80 = __half2float(prow[255 + (L0 >> 1)]);
    float p81 = __half2float(prow[256 + (L0 >> 1)]);
    float p82 = __half2float(prow[257 + (L0 >> 1)]);
    float p83 = __half2float(prow[258 + (L0 >> 1)]);
    float u1 = pref * p6, u0 = pref - u1;
    float v01 = u0 * p7a, v00 = u0 - v01;
    float v11 = u1 * p7b, v10 = u1 - v11;
    float pr1 = v00 * p80, pr0 = v00 - pr1;
    float pr3 = v01 * p81, pr2 = v01 - pr3;
    float pr5 = v10 * p82, pr4 = v10 - pr5;
    float pr7 = v11 * p83, pr6 = v11 - pr7;
    f16x8 af;
    af[0] = (_Float16)pr0; af[1] = (_Float16)pr1;
    af[2] = (_Float16)pr2; af[3] = (_Float16)pr3;
    af[4] = (_Float16)pr4; af[5] = (_Float16)pr5;
    af[6] = (_Float16)pr6; af[7] = (_Float16)pr7;
    acc = __builtin_amdgcn_mfma_f32_16x16x32_f16(af, bfr[tt], acc, 0, 0, 0);
  }

  red[wid][lane] = acc;
  __syncthreads();
  if (wid == 0 && col < 10) {
    f32x4 a0 = red[0][lane], a1 = red[1][lane], a2 = red[2][lane], a3 = red[3][lane];
#pragma unroll
    for (int q = 0; q < 4; ++q)
      out[(size_t)(rbase + g * 4 + q) * 10 + col] = a0[q] + a1[q] + a2[q] + a3[q];
  }
}

// ---------------------------------------------------------------------------
extern "C" void kernel_launch(void* const* d_in, const int* in_sizes, int n_in,
                              void* d_out, int out_size, void* d_ws, size_t ws_size,
                              hipStream_t stream) {
  const float* X = (const float*)d_in[0];
  const float* W = (const float*)d_in[1];
  const float* bv = (const float*)d_in[2];
  const float* LL = (const float*)d_in[3];
  float* out = (float*)d_out;

  __half* P = (__half*)d_ws;                                          // 16 MB
  _Float16* Bpk = (_Float16*)((char*)d_ws + (size_t)16384 * 512 * 2); // 1 MB

  prep_b<<<128, 256, 0, stream>>>(W, Bpk);
  gemm_sig<<<256, 1024, 0, stream>>>(X, Bpk, bv, P);
  tree_out<<<1024, 256, 0, stream>>>(P, LL, out);
}